// Round 7
// baseline (785.049 us; speedup 1.0000x reference)
//
#include <hip/hip_runtime.h>
#include <math.h>

// Problem constants (fixed by setup_inputs: B=4, D=128, T=8, P=4096)
#define BB 4
#define DD 128
#define TT 8
#define PP 4096
#define KK 10
#define NT 7              // T-1 frame pairs
#define BP (BB*PP)        // 16384 points per frame across batch
#define NQ (NT*BP)        // 114688 total queries
#define NBLK_COS 896
#define QPB 128           // queries per block in cos kernel (NBLK_COS*QPB == NQ)

#define CHUNKS 4
#define CSZ (PP/CHUNKS)   // 1024 candidates per chunk
#define SELCAP 16         // candidate-record capacity in collect (>=10 + eps window)

// Workspace layout (bytes). part (18.35 MB) and cand4 (2 MB @20 MB) both
// alias the featT region (58.7 MB): fully consumed by knn_collect BEFORE
// transpose_kernel writes featT (same-stream ordering).
#define OFF_FEATT 0u                 // NQ*DD floats  = 58,720,256 B
#define OFF_PARTV 0u                 // CHUNKS*KK*NQ uints = 18,350,080 B
#define OFF_CAND4 20971520u          // BB*TT*PP float4 = 2,097,152 B
#define OFF_IDX   58720256u          // NQ*KK ints    =  4,587,520 B
#define OFF_DV    63307776u          // NQ floats     =    458,752 B
#define OFF_NORM  63766528u          // NQ floats     =    458,752 B
#define OFF_SCALE 64225280u          // NT floats (padded to 256)
#define OFF_PART  64225536u          // NBLK_COS floats

// NOTE: __builtin_amdgcn_cvt_pkrtz returns __fp16 ext_vector_type(2) — use
// that exact element type (round-6 compile fix).
typedef __fp16 f16x2 __attribute__((ext_vector_type(2)));
union H2U { f16x2 h; unsigned u; };

// md = |q-c|^2 computed as (xx_q + xx_c) - 2*inner. Same helper everywhere.
__device__ __forceinline__ float md_of(const float4 q, const float4 c) {
  float s = q.w + c.w;
  float inner = fmaf(q.x, c.x, fmaf(q.y, c.y, q.z * c.z));
  return fmaf(-2.0f, inner, s);
}

// Packed-f16 "keep 10 smallest" ladder over two independent candidate
// streams (.x / .y). Values are conservative UPPER bounds of md:
// cvt_pkrtz (round toward zero) then +2 f16-ulps. 21 VALU per 2 candidates.
// Uses __builtin_elementwise_min/max on native f16x2 -> v_pk_min/max_f16.
__device__ __forceinline__ void ins2(f16x2 (&bv)[KK], float mdA, float mdB) {
  H2U cv;
  cv.h = __builtin_amdgcn_cvt_pkrtz(mdA, mdB);
  cv.u += 0x00020002u;  // +2 ulps up (values are small positive; no NaN/ovf)
  bv[KK - 1] = __builtin_elementwise_min(bv[KK - 1], cv.h);
#pragma unroll
  for (int i = KK - 1; i > 0; --i) {
    f16x2 lo = __builtin_elementwise_min(bv[i - 1], bv[i]);
    f16x2 hi = __builtin_elementwise_max(bv[i - 1], bv[i]);
    bv[i - 1] = lo;
    bv[i] = hi;
  }
}
__device__ __forceinline__ void insh(f16x2 (&bv)[KK], f16x2 h) {
  bv[KK - 1] = __builtin_elementwise_min(bv[KK - 1], h);
#pragma unroll
  for (int i = KK - 1; i > 0; --i) {
    f16x2 lo = __builtin_elementwise_min(bv[i - 1], bv[i]);
    f16x2 hi = __builtin_elementwise_max(bv[i - 1], bv[i]);
    bv[i - 1] = lo;
    bv[i] = hi;
  }
}

// f32 keep-10-smallest (values only), branchless.
__device__ __forceinline__ void insf(float (&bv)[KK], float v) {
  bv[KK - 1] = fminf(bv[KK - 1], v);
#pragma unroll
  for (int i = KK - 1; i > 0; --i) {
    float lo = fminf(bv[i - 1], bv[i]);
    float hi = fmaxf(bv[i - 1], bv[i]);
    bv[i - 1] = lo;
    bv[i] = hi;
  }
}

// Exact stable (md,idx) insert: keep 10 smallest, ascending md; strict-<
// entry/bubble over an ascending-j stream keeps earlier index on ties —
// exactly jax.lax.top_k's tie rule.
__device__ __forceinline__ void insp(float (&v)[KK], int (&vi)[KK], float md,
                                     int j) {
  bool en = md < v[KK - 1];
  v[KK - 1] = en ? md : v[KK - 1];
  vi[KK - 1] = en ? j : vi[KK - 1];
#pragma unroll
  for (int i = KK - 1; i > 0; --i) {
    bool sw = v[i] < v[i - 1];
    float tv = sw ? v[i - 1] : v[i];
    v[i - 1] = sw ? v[i] : v[i - 1];
    v[i] = tv;
    int ti = sw ? vi[i - 1] : vi[i];
    vi[i - 1] = sw ? vi[i] : vi[i - 1];
    vi[i] = ti;
  }
}

// Register scatter by runtime slot (unroll-literal indices -> stays in VGPRs).
__device__ __forceinline__ void rec16(int (&a)[SELCAP], int cnt, int j) {
#pragma unroll
  for (int r = 0; r < SELCAP; ++r) a[r] = (cnt == r) ? j : a[r];
}

// ---------------------------------------------------------------------------
// Kernel P: precompute (x,y,z,xx) per point so scan kernels read it directly.
// ---------------------------------------------------------------------------
__global__ __launch_bounds__(256) void prep_cand(
    const float* __restrict__ pts4, float4* __restrict__ cand4) {
  const int i = blockIdx.x * 256 + threadIdx.x;  // over BB*TT*PP
  float4 v = ((const float4*)pts4)[i];
  v.w = fmaf(v.x, v.x, fmaf(v.y, v.y, v.z * v.z));
  cand4[i] = v;
}

// ---------------------------------------------------------------------------
// Kernel A1: per-chunk top-10 conservative f16 upper bounds of md (no LDS —
// candidate reads are wave-uniform -> scalar loads; two packed ladders).
// ---------------------------------------------------------------------------
__global__ __launch_bounds__(256) void knn_thr_partial(
    const float4* __restrict__ cand4, unsigned* __restrict__ part) {
  const int qg = blockIdx.x >> 2;  // query group 0..15
  const int c = blockIdx.x & 3;    // chunk 0..3
  const int b = blockIdx.y, t = blockIdx.z;
  const float4* __restrict__ src = cand4 + ((size_t)(b * TT + t) * PP);
  const float4* __restrict__ ch = src + c * CSZ;

  const int p = qg * 256 + threadIdx.x;
  const float4 q = src[p];

  H2U inf2;
  inf2.u = 0x7C007C00u;
  f16x2 l1[KK], l2[KK];
#pragma unroll
  for (int i = 0; i < KK; ++i) { l1[i] = inf2.h; l2[i] = inf2.h; }

  for (int j = 0; j < CSZ; j += 4) {
    float4 c0 = ch[j], c1 = ch[j + 1], c2 = ch[j + 2], c3 = ch[j + 3];
    float md0 = md_of(q, c0);
    float md1 = md_of(q, c1);
    float md2 = md_of(q, c2);
    float md3 = md_of(q, c3);
    ins2(l1, md0, md1);
    ins2(l2, md2, md3);
  }
  // merge stream-pairs: l1 <- per-component union top-10
#pragma unroll
  for (int r = 0; r < KK; ++r) insh(l1, l2[r]);

  const size_t qid = (size_t)(t * BB + b) * PP + p;
#pragma unroll
  for (int r = 0; r < KK; ++r) {
    H2U w;
    w.h = l1[r];
    part[(size_t)(c * KK + r) * NQ + qid] = w.u;
  }
}

// ---------------------------------------------------------------------------
// Kernel B: permissive threshold tau from the 80 f16 bounds, full rescan with
// load-free filter body (record indices only), exact stable top-10 + disp_var
// in the epilogue. Exactness: every true top-10 member has md <= md_thr <=
// tau (upper-bound tournament + 1e-4 margin >> all fp slop).
// ---------------------------------------------------------------------------
__global__ __launch_bounds__(256) void knn_collect(
    const float4* __restrict__ cand4, const float* __restrict__ pts4,
    const unsigned* __restrict__ part, int* __restrict__ idx_out,
    float* __restrict__ dv_out) {
  __shared__ float4 cand[PP];  // 64 KB (already has xx in .w)
  const int qg = blockIdx.x;
  const int b = blockIdx.y, t = blockIdx.z;
  const float4* __restrict__ src = cand4 + ((size_t)(b * TT + t) * PP);
  const float4* __restrict__ src1 =
      (const float4*)pts4 + ((size_t)(b * TT + t + 1) * PP);

  for (int i = threadIdx.x; i < PP; i += 256) cand[i] = src[i];
  __syncthreads();

  const int p = qg * 256 + threadIdx.x;
  const size_t g = (size_t)(t * BB + b) * PP + p;

  // tau = exact 10th-smallest of the 80 per-stream f16 upper bounds + margin
  float bv[KK];
#pragma unroll
  for (int i = 0; i < KK; ++i) bv[i] = INFINITY;
#pragma unroll
  for (int c = 0; c < CHUNKS; ++c) {
#pragma unroll
    for (int r = 0; r < KK; ++r) {
      H2U w;
      w.u = part[(size_t)(c * KK + r) * NQ + g];
      insf(bv, (float)w.h.x);
      insf(bv, (float)w.h.y);
    }
  }
  const float tau = bv[KK - 1] + 1e-4f;

  const float4 q = cand[p];

  int sel[SELCAP];
#pragma unroll
  for (int r = 0; r < SELCAP; ++r) sel[r] = 0;
  int cnt = 0;

  for (int j = 0; j < PP; j += 8) {
    float4 c0 = cand[j], c1 = cand[j + 1], c2 = cand[j + 2], c3 = cand[j + 3];
    float4 c4 = cand[j + 4], c5 = cand[j + 5], c6 = cand[j + 6],
           c7 = cand[j + 7];
    float m0 = md_of(q, c0), m1 = md_of(q, c1), m2 = md_of(q, c2),
          m3 = md_of(q, c3);
    float m4 = md_of(q, c4), m5 = md_of(q, c5), m6 = md_of(q, c6),
          m7 = md_of(q, c7);
#define FLT(mm, jj)                          \
    if ((mm) <= tau) { rec16(sel, cnt, (jj)); ++cnt; }
    FLT(m0, j); FLT(m1, j + 1); FLT(m2, j + 2); FLT(m3, j + 3);
    FLT(m4, j + 4); FLT(m5, j + 5); FLT(m6, j + 6); FLT(m7, j + 7);
#undef FLT
  }

  // ---- epilogue: exact stable top-10 among recorded (ascending-j order)
  float v[KK];
  int vi[KK];
#pragma unroll
  for (int i = 0; i < KK; ++i) { v[i] = INFINITY; vi[i] = 0; }
  const int m = cnt < SELCAP ? cnt : SELCAP;
#pragma unroll
  for (int r = 0; r < SELCAP; ++r) {
    if (r < m) {
      int j = sel[r];
      insp(v, vi, md_of(q, cand[j]), j);
    }
  }

  // disp_var over the 10 selected, in rank order (matches top_k order)
  float4 a1 = src1[p];
  const float dqx = a1.x - q.x, dqy = a1.y - q.y, dqz = a1.z - q.z;
  float s = 0.0f;
  int* myidx = idx_out + g * KK;
#pragma unroll
  for (int r = 0; r < KK; ++r) {
    int j = vi[r];
    float4 cc = cand[j];
    float4 n1 = src1[j];
    float dx = (n1.x - cc.x) - dqx;
    float dy = (n1.y - cc.y) - dqy;
    float dz = (n1.z - cc.z) - dqz;
    s += fmaf(dx, dx, fmaf(dy, dy, dz * dz));
    myidx[r] = j;
  }
  dv_out[g] = s * (1.0f / KK);
}

// ---------------------------------------------------------------------------
// Kernel B2: transpose encoded[b][d][t*P+p] -> featT[t][b][p][d]  (t < NT)
// ---------------------------------------------------------------------------
__global__ __launch_bounds__(256) void transpose_kernel(
    const float* __restrict__ encoded, float* __restrict__ featT) {
  __shared__ float tile[32][33];
  const int slice = blockIdx.z;  // t*BB + b
  const int t = slice / BB, b = slice % BB;
  const int p0 = blockIdx.x * 32, d0 = blockIdx.y * 32;
  const int tx = threadIdx.x, ty = threadIdx.y;
#pragma unroll
  for (int r = 0; r < 4; ++r) {
    int d = d0 + ty + r * 8;
    tile[ty + r * 8][tx] =
        encoded[((size_t)(b * DD + d)) * (TT * PP) + (size_t)t * PP + p0 + tx];
  }
  __syncthreads();
#pragma unroll
  for (int r = 0; r < 4; ++r) {
    int p = p0 + ty + r * 8;
    featT[((size_t)slice * PP + p) * DD + d0 + tx] = tile[tx][ty + r * 8];
  }
}

// ---------------------------------------------------------------------------
// Kernel N: per-point feature L2 norms (wave per point)
// ---------------------------------------------------------------------------
__global__ __launch_bounds__(256) void norms_kernel(
    const float* __restrict__ featT, float* __restrict__ norms) {
  const int w = threadIdx.x >> 6, lane = threadIdx.x & 63;
  const int wid = blockIdx.x * 4 + w;
  for (int i = 0; i < 32; ++i) {
    const int g = wid * 32 + i;
    float2 f = *(const float2*)(featT + (size_t)g * DD + lane * 2);
    float part = fmaf(f.x, f.x, f.y * f.y);
#pragma unroll
    for (int o = 32; o > 0; o >>= 1) part += __shfl_xor(part, o);
    if (lane == 0) norms[g] = sqrtf(part);
  }
}

// ---------------------------------------------------------------------------
// Kernel C: exact lower-median per t via 4-pass radix select on float bits
// ---------------------------------------------------------------------------
__global__ __launch_bounds__(256) void median_kernel(
    const float* __restrict__ disp_var, float* __restrict__ scale) {
  const int t = blockIdx.x;
  const unsigned* u = (const unsigned*)(disp_var + (size_t)t * BP);
  __shared__ unsigned hist[256];
  __shared__ unsigned sh_prefix;
  __shared__ int sh_rank;
  if (threadIdx.x == 0) { sh_prefix = 0u; sh_rank = (BP - 1) >> 1; }
  __syncthreads();
  for (int pass = 0; pass < 4; ++pass) {
    const int shift = 24 - pass * 8;
    hist[threadIdx.x] = 0u;
    __syncthreads();
    const unsigned hmask = (pass == 0) ? 0u : (0xFFFFFFFFu << (shift + 8));
    const unsigned prefix = sh_prefix;
    for (int i = threadIdx.x; i < BP; i += 256) {
      unsigned v = u[i];
      if ((v & hmask) == prefix) atomicAdd(&hist[(v >> shift) & 255u], 1u);
    }
    __syncthreads();
    if (threadIdx.x == 0) {
      int rank = sh_rank;
      unsigned run = 0u;
      for (int c = 0; c < 256; ++c) {
        unsigned h = hist[c];
        if (run + h > (unsigned)rank) {
          sh_rank = rank - (int)run;
          sh_prefix = prefix | ((unsigned)c << shift);
          break;
        }
        run += h;
      }
    }
    __syncthreads();
  }
  if (threadIdx.x == 0) {
    float med = __uint_as_float(sh_prefix);
    scale[t] = fmaxf(med, 1e-6f);
  }
}

// ---------------------------------------------------------------------------
// Kernel D: cosine similarity + rigidity loss, deterministic block partials
// ---------------------------------------------------------------------------
__global__ __launch_bounds__(256) void cos_loss_kernel(
    const float* __restrict__ featT, const int* __restrict__ idxw,
    const float* __restrict__ norms, const float* __restrict__ dv,
    const float* __restrict__ scale, float* __restrict__ partial) {
  const int w = threadIdx.x >> 6, lane = threadIdx.x & 63;
  __shared__ float wsum[4];
  float acc = 0.0f;
  const int qbase = blockIdx.x * QPB + w * (QPB / 4);
  for (int i = 0; i < QPB / 4; ++i) {
    const int g = qbase + i;
    const int t = g >> 14;
    const int p = g & (PP - 1);
    const int slice = g - p;  // base of this (t,b) slice
    const float* fbase = featT + (size_t)g * DD;
    float2 fq = *(const float2*)(fbase + lane * 2);
    float nq = fmaxf(norms[g], 1e-8f);
    const int* ip = idxw + (size_t)g * KK;
    float msum = 0.0f;
#pragma unroll
    for (int k = 0; k < KK; ++k) {
      int j = ip[k];
      const float* nb = featT + (size_t)(slice + j) * DD;
      float2 fn = *(const float2*)(nb + lane * 2);
      float part = fmaf(fq.x, fn.x, fq.y * fn.y);
#pragma unroll
      for (int o = 32; o > 0; o >>= 1) part += __shfl_xor(part, o);
      float nn = fmaxf(norms[slice + j], 1e-8f);
      msum += part / (nq * nn);
    }
    float mean_sim = msum * (1.0f / KK);
    float rig = expf(-dv[g] / scale[t]);
    acc += rig * (1.0f - mean_sim);
  }
  if (lane == 0) wsum[w] = acc;
  __syncthreads();
  if (threadIdx.x == 0)
    partial[blockIdx.x] = (wsum[0] + wsum[1]) + (wsum[2] + wsum[3]);
}

// ---------------------------------------------------------------------------
// Kernel E: final deterministic reduce -> scalar loss
// ---------------------------------------------------------------------------
__global__ __launch_bounds__(256) void final_reduce_kernel(
    const float* __restrict__ partial, float* __restrict__ out) {
  __shared__ float sh[256];
  float s = 0.0f;
  for (int i = threadIdx.x; i < NBLK_COS; i += 256) s += partial[i];
  sh[threadIdx.x] = s;
  __syncthreads();
  for (int st = 128; st > 0; st >>= 1) {
    if (threadIdx.x < st) sh[threadIdx.x] += sh[threadIdx.x + st];
    __syncthreads();
  }
  if (threadIdx.x == 0) out[0] = sh[0] * (1.0f / (float)NQ);
}

extern "C" void kernel_launch(void* const* d_in, const int* in_sizes, int n_in,
                              void* d_out, int out_size, void* d_ws,
                              size_t ws_size, hipStream_t stream) {
  const float* encoded = (const float*)d_in[0];
  const float* pts4 = (const float*)d_in[1];
  char* ws = (char*)d_ws;
  float* featT = (float*)(ws + OFF_FEATT);
  unsigned* part = (unsigned*)(ws + OFF_PARTV);  // aliases featT (consumed 1st)
  float4* cand4 = (float4*)(ws + OFF_CAND4);     // aliases featT (consumed 1st)
  int* idxw = (int*)(ws + OFF_IDX);
  float* dv = (float*)(ws + OFF_DV);
  float* norms = (float*)(ws + OFF_NORM);
  float* scale = (float*)(ws + OFF_SCALE);
  float* partial = (float*)(ws + OFF_PART);
  float* outp = (float*)d_out;

  prep_cand<<<(BB * TT * PP) / 256, 256, 0, stream>>>(pts4, cand4);
  knn_thr_partial<<<dim3(16 * CHUNKS, BB, NT), 256, 0, stream>>>(cand4, part);
  knn_collect<<<dim3(16, BB, NT), 256, 0, stream>>>(cand4, pts4, part, idxw,
                                                    dv);
  transpose_kernel<<<dim3(PP / 32, DD / 32, NT * BB), dim3(32, 8), 0, stream>>>(
      encoded, featT);
  norms_kernel<<<NBLK_COS, 256, 0, stream>>>(featT, norms);
  median_kernel<<<NT, 256, 0, stream>>>(dv, scale);
  cos_loss_kernel<<<NBLK_COS, 256, 0, stream>>>(featT, idxw, norms, dv, scale,
                                                partial);
  final_reduce_kernel<<<1, 256, 0, stream>>>(partial, outp);
}

// Round 8
// 737.717 us; speedup vs baseline: 1.0642x; 1.0642x over previous
//
#include <hip/hip_runtime.h>
#include <math.h>

// Problem constants (fixed by setup_inputs: B=4, D=128, T=8, P=4096)
#define BB 4
#define DD 128
#define TT 8
#define PP 4096
#define KK 10
#define NT 7              // T-1 frame pairs
#define BP (BB*PP)        // 16384 points per frame across batch
#define NQ (NT*BP)        // 114688 total queries
#define NBLK_COS 896
#define QPB 128           // queries per block in cos kernel (NBLK_COS*QPB == NQ)

#define CHUNKS 4
#define CSZ (PP/CHUNKS)   // 1024 candidates per chunk
#define FCAP 12           // per-chunk recorded-index cap (typ ~3, worst ~11)

// Workspace layout (bytes). Everything below OFF_IDX aliases the featT
// region (58.7 MB) and is fully consumed by knn_finish BEFORE
// transpose_kernel writes featT (same-stream ordering).
#define OFF_FEATT 0u                 // NQ*DD floats  = 58,720,256 B
#define OFF_PARTV 0u                 // CHUNKS*KK*NQ uints = 18,350,080 B
#define OFF_CAND4 20971520u          // BB*TT*PP float4 = 2,097,152 B
#define OFF_TAU   23068672u          // NQ floats = 458,752 B
#define OFF_FCNT  23527424u          // CHUNKS*NQ uints = 1,835,008 B
#define OFF_FLIST 25362432u          // CHUNKS*FCAP*NQ u16 = 11,010,048 B (ends 36.4 MB)
#define OFF_IDX   58720256u          // NQ*KK ints    =  4,587,520 B
#define OFF_DV    63307776u          // NQ floats     =    458,752 B
#define OFF_NORM  63766528u          // NQ floats     =    458,752 B
#define OFF_SCALE 64225280u          // NT floats (padded to 256)
#define OFF_PART  64225536u          // NBLK_COS floats

// __builtin_amdgcn_cvt_pkrtz returns __fp16 ext_vector_type(2).
typedef __fp16 f16x2 __attribute__((ext_vector_type(2)));
union H2U { f16x2 h; unsigned u; };

// md = |q-c|^2 computed as (xx_q + xx_c) - 2*inner. MUST be the same
// expression in every kernel (bit-identical md values are what make the
// f16-upper-bound threshold argument exact).
__device__ __forceinline__ float md_of(const float4 q, const float4 c) {
  float s = q.w + c.w;
  float inner = fmaf(q.x, c.x, fmaf(q.y, c.y, q.z * c.z));
  return fmaf(-2.0f, inner, s);
}

// Packed-f16 "keep 10 smallest" ladder over two independent candidate
// streams (.x / .y). Values are conservative UPPER bounds of md:
// cvt_pkrtz (round toward zero... toward zero = down for positives) then
// +2 f16-ulps. ub(md) is monotone non-decreasing in md.
__device__ __forceinline__ void ins2(f16x2 (&bv)[KK], float mdA, float mdB) {
  H2U cv;
  cv.h = __builtin_amdgcn_cvt_pkrtz(mdA, mdB);
  cv.u += 0x00020002u;  // +2 ulps up (values small positive; no NaN/ovf)
  bv[KK - 1] = __builtin_elementwise_min(bv[KK - 1], cv.h);
#pragma unroll
  for (int i = KK - 1; i > 0; --i) {
    f16x2 lo = __builtin_elementwise_min(bv[i - 1], bv[i]);
    f16x2 hi = __builtin_elementwise_max(bv[i - 1], bv[i]);
    bv[i - 1] = lo;
    bv[i] = hi;
  }
}
__device__ __forceinline__ void insh(f16x2 (&bv)[KK], f16x2 h) {
  bv[KK - 1] = __builtin_elementwise_min(bv[KK - 1], h);
#pragma unroll
  for (int i = KK - 1; i > 0; --i) {
    f16x2 lo = __builtin_elementwise_min(bv[i - 1], bv[i]);
    f16x2 hi = __builtin_elementwise_max(bv[i - 1], bv[i]);
    bv[i - 1] = lo;
    bv[i] = hi;
  }
}

// f32 keep-10-smallest (values only), branchless.
__device__ __forceinline__ void insf(float (&bv)[KK], float v) {
  bv[KK - 1] = fminf(bv[KK - 1], v);
#pragma unroll
  for (int i = KK - 1; i > 0; --i) {
    float lo = fminf(bv[i - 1], bv[i]);
    float hi = fmaxf(bv[i - 1], bv[i]);
    bv[i - 1] = lo;
    bv[i] = hi;
  }
}

// Exact stable (md,idx) insert: keep 10 smallest, ascending md; strict-<
// entry/bubble over an ascending-j insert stream keeps earlier index on
// ties — exactly jax.lax.top_k's tie rule.
__device__ __forceinline__ void insp(float (&v)[KK], int (&vi)[KK], float md,
                                     int j) {
  bool en = md < v[KK - 1];
  v[KK - 1] = en ? md : v[KK - 1];
  vi[KK - 1] = en ? j : vi[KK - 1];
#pragma unroll
  for (int i = KK - 1; i > 0; --i) {
    bool sw = v[i] < v[i - 1];
    float tv = sw ? v[i - 1] : v[i];
    v[i - 1] = sw ? v[i] : v[i - 1];
    v[i] = tv;
    int ti = sw ? vi[i - 1] : vi[i];
    vi[i - 1] = sw ? vi[i] : vi[i - 1];
    vi[i] = ti;
  }
}

// Register scatter by runtime slot (unroll-literal indices -> stays in VGPRs).
__device__ __forceinline__ void rec12(int (&a)[FCAP], int cnt, int j) {
#pragma unroll
  for (int r = 0; r < FCAP; ++r) a[r] = (cnt == r) ? j : a[r];
}

// ---------------------------------------------------------------------------
// Kernel P: precompute (x,y,z,xx) per point.
// ---------------------------------------------------------------------------
__global__ __launch_bounds__(256) void prep_cand(
    const float* __restrict__ pts4, float4* __restrict__ cand4) {
  const int i = blockIdx.x * 256 + threadIdx.x;  // over BB*TT*PP
  float4 v = ((const float4*)pts4)[i];
  v.w = fmaf(v.x, v.x, fmaf(v.y, v.y, v.z * v.z));
  cand4[i] = v;
}

// ---------------------------------------------------------------------------
// Kernel A1: per-chunk top-10 conservative f16 upper bounds of md (no LDS —
// candidate reads are wave-uniform -> scalar loads; two packed ladders).
// ---------------------------------------------------------------------------
__global__ __launch_bounds__(256) void knn_thr_partial(
    const float4* __restrict__ cand4, unsigned* __restrict__ part) {
  const int qg = blockIdx.x >> 2;  // query group 0..15
  const int c = blockIdx.x & 3;    // chunk 0..3
  const int b = blockIdx.y, t = blockIdx.z;
  const float4* __restrict__ src = cand4 + ((size_t)(b * TT + t) * PP);
  const float4* __restrict__ ch = src + c * CSZ;

  const int p = qg * 256 + threadIdx.x;
  const float4 q = src[p];

  H2U inf2;
  inf2.u = 0x7C007C00u;
  f16x2 l1[KK], l2[KK];
#pragma unroll
  for (int i = 0; i < KK; ++i) { l1[i] = inf2.h; l2[i] = inf2.h; }

  for (int j = 0; j < CSZ; j += 4) {
    float4 c0 = ch[j], c1 = ch[j + 1], c2 = ch[j + 2], c3 = ch[j + 3];
    float md0 = md_of(q, c0);
    float md1 = md_of(q, c1);
    float md2 = md_of(q, c2);
    float md3 = md_of(q, c3);
    ins2(l1, md0, md1);
    ins2(l2, md2, md3);
  }
  // merge stream-pairs: l1 <- per-component union top-10
#pragma unroll
  for (int r = 0; r < KK; ++r) insh(l1, l2[r]);

  const size_t qid = (size_t)(t * BB + b) * PP + p;
#pragma unroll
  for (int r = 0; r < KK; ++r) {
    H2U w;
    w.h = l1[r];
    part[(size_t)(c * KK + r) * NQ + qid] = w.u;
  }
}

// ---------------------------------------------------------------------------
// Kernel T: tau[g] = 10th-smallest of the 80 stored f16 upper bounds + eps.
// Guarantee: every true top-10 member m has md_m <= tau (ub monotone in md,
// so at most 9 stored values are strictly below ub(md_10)).
// ---------------------------------------------------------------------------
__global__ __launch_bounds__(256) void tau_kernel(
    const unsigned* __restrict__ part, float* __restrict__ tau_arr) {
  const int g = blockIdx.x * 256 + threadIdx.x;
  float bv[KK];
#pragma unroll
  for (int i = 0; i < KK; ++i) bv[i] = INFINITY;
#pragma unroll
  for (int c = 0; c < CHUNKS; ++c) {
#pragma unroll
    for (int r = 0; r < KK; ++r) {
      H2U w;
      w.u = part[(size_t)(c * KK + r) * NQ + g];
      insf(bv, (float)w.h.x);
      insf(bv, (float)w.h.y);
    }
  }
  tau_arr[g] = bv[KK - 1] + 1e-4f;
}

// ---------------------------------------------------------------------------
// Kernel F: chunked filter. Same high-occupancy no-LDS structure as A1:
// each block scans ONE 1024-candidate chunk for 256 queries; records global
// indices with md <= tau (<=12 per chunk, ascending j) + count.
// ---------------------------------------------------------------------------
__global__ __launch_bounds__(256) void knn_filter(
    const float4* __restrict__ cand4, const float* __restrict__ tau_arr,
    unsigned* __restrict__ fcnt, unsigned short* __restrict__ flist) {
  const int qg = blockIdx.x >> 2;  // query group 0..15
  const int c = blockIdx.x & 3;    // chunk 0..3
  const int b = blockIdx.y, t = blockIdx.z;
  const float4* __restrict__ src = cand4 + ((size_t)(b * TT + t) * PP);
  const float4* __restrict__ ch = src + c * CSZ;
  const int jbase = c * CSZ;

  const int p = qg * 256 + threadIdx.x;
  const size_t g = (size_t)(t * BB + b) * PP + p;
  const float4 q = src[p];
  const float tau = tau_arr[g];

  int sel[FCAP];
#pragma unroll
  for (int r = 0; r < FCAP; ++r) sel[r] = 0;
  int cnt = 0;

  for (int j = 0; j < CSZ; j += 8) {
    float4 c0 = ch[j], c1 = ch[j + 1], c2 = ch[j + 2], c3 = ch[j + 3];
    float4 c4 = ch[j + 4], c5 = ch[j + 5], c6 = ch[j + 6], c7 = ch[j + 7];
    float m0 = md_of(q, c0), m1 = md_of(q, c1), m2 = md_of(q, c2),
          m3 = md_of(q, c3);
    float m4 = md_of(q, c4), m5 = md_of(q, c5), m6 = md_of(q, c6),
          m7 = md_of(q, c7);
#define FLT(mm, jj)                                         \
    if ((mm) <= tau) { rec12(sel, cnt, jbase + (jj)); ++cnt; }
    FLT(m0, j); FLT(m1, j + 1); FLT(m2, j + 2); FLT(m3, j + 3);
    FLT(m4, j + 4); FLT(m5, j + 5); FLT(m6, j + 6); FLT(m7, j + 7);
#undef FLT
  }

  fcnt[(size_t)c * NQ + g] = (unsigned)cnt;
#pragma unroll
  for (int r = 0; r < FCAP; ++r)
    flist[(size_t)(c * FCAP + r) * NQ + g] = (unsigned short)sel[r];
}

// ---------------------------------------------------------------------------
// Kernel G: finish. Per query: gather the <=48 recorded candidates
// (ascending j across chunks), exact stable (md,idx) top-10, disp_var.
// ---------------------------------------------------------------------------
__global__ __launch_bounds__(256) void knn_finish(
    const float4* __restrict__ cand4, const float* __restrict__ pts4,
    const unsigned* __restrict__ fcnt, const unsigned short* __restrict__ flist,
    int* __restrict__ idx_out, float* __restrict__ dv_out) {
  const int g = blockIdx.x * 256 + threadIdx.x;
  const int t = g >> 14;
  const int rem = g & (BP - 1);
  const int b = rem >> 12;
  const int p = rem & (PP - 1);
  const float4* __restrict__ src = cand4 + ((size_t)(b * TT + t) * PP);
  const float4* __restrict__ src1 =
      (const float4*)pts4 + ((size_t)(b * TT + t + 1) * PP);

  const float4 q = src[p];

  float v[KK];
  int vi[KK];
#pragma unroll
  for (int i = 0; i < KK; ++i) { v[i] = INFINITY; vi[i] = 0; }

#pragma unroll
  for (int c = 0; c < CHUNKS; ++c) {
    int cn = (int)fcnt[(size_t)c * NQ + g];
    cn = cn < FCAP ? cn : FCAP;
#pragma unroll
    for (int r = 0; r < FCAP; ++r) {
      if (r < cn) {
        int j = (int)flist[(size_t)(c * FCAP + r) * NQ + g];
        insp(v, vi, md_of(q, src[j]), j);
      }
    }
  }

  // disp_var over the 10 selected, in rank order (matches top_k order)
  float4 a1 = src1[p];
  const float dqx = a1.x - q.x, dqy = a1.y - q.y, dqz = a1.z - q.z;
  float s = 0.0f;
  int* myidx = idx_out + (size_t)g * KK;
#pragma unroll
  for (int r = 0; r < KK; ++r) {
    int j = vi[r];
    float4 cc = src[j];
    float4 n1 = src1[j];
    float dx = (n1.x - cc.x) - dqx;
    float dy = (n1.y - cc.y) - dqy;
    float dz = (n1.z - cc.z) - dqz;
    s += fmaf(dx, dx, fmaf(dy, dy, dz * dz));
    myidx[r] = j;
  }
  dv_out[g] = s * (1.0f / KK);
}

// ---------------------------------------------------------------------------
// Kernel B2: transpose encoded[b][d][t*P+p] -> featT[t][b][p][d]  (t < NT)
// ---------------------------------------------------------------------------
__global__ __launch_bounds__(256) void transpose_kernel(
    const float* __restrict__ encoded, float* __restrict__ featT) {
  __shared__ float tile[32][33];
  const int slice = blockIdx.z;  // t*BB + b
  const int t = slice / BB, b = slice % BB;
  const int p0 = blockIdx.x * 32, d0 = blockIdx.y * 32;
  const int tx = threadIdx.x, ty = threadIdx.y;
#pragma unroll
  for (int r = 0; r < 4; ++r) {
    int d = d0 + ty + r * 8;
    tile[ty + r * 8][tx] =
        encoded[((size_t)(b * DD + d)) * (TT * PP) + (size_t)t * PP + p0 + tx];
  }
  __syncthreads();
#pragma unroll
  for (int r = 0; r < 4; ++r) {
    int p = p0 + ty + r * 8;
    featT[((size_t)slice * PP + p) * DD + d0 + tx] = tile[tx][ty + r * 8];
  }
}

// ---------------------------------------------------------------------------
// Kernel N: per-point feature L2 norms (wave per point)
// ---------------------------------------------------------------------------
__global__ __launch_bounds__(256) void norms_kernel(
    const float* __restrict__ featT, float* __restrict__ norms) {
  const int w = threadIdx.x >> 6, lane = threadIdx.x & 63;
  const int wid = blockIdx.x * 4 + w;
  for (int i = 0; i < 32; ++i) {
    const int g = wid * 32 + i;
    float2 f = *(const float2*)(featT + (size_t)g * DD + lane * 2);
    float part = fmaf(f.x, f.x, f.y * f.y);
#pragma unroll
    for (int o = 32; o > 0; o >>= 1) part += __shfl_xor(part, o);
    if (lane == 0) norms[g] = sqrtf(part);
  }
}

// ---------------------------------------------------------------------------
// Kernel C: exact lower-median per t via 4-pass radix select on float bits
// ---------------------------------------------------------------------------
__global__ __launch_bounds__(256) void median_kernel(
    const float* __restrict__ disp_var, float* __restrict__ scale) {
  const int t = blockIdx.x;
  const unsigned* u = (const unsigned*)(disp_var + (size_t)t * BP);
  __shared__ unsigned hist[256];
  __shared__ unsigned sh_prefix;
  __shared__ int sh_rank;
  if (threadIdx.x == 0) { sh_prefix = 0u; sh_rank = (BP - 1) >> 1; }
  __syncthreads();
  for (int pass = 0; pass < 4; ++pass) {
    const int shift = 24 - pass * 8;
    hist[threadIdx.x] = 0u;
    __syncthreads();
    const unsigned hmask = (pass == 0) ? 0u : (0xFFFFFFFFu << (shift + 8));
    const unsigned prefix = sh_prefix;
    for (int i = threadIdx.x; i < BP; i += 256) {
      unsigned v = u[i];
      if ((v & hmask) == prefix) atomicAdd(&hist[(v >> shift) & 255u], 1u);
    }
    __syncthreads();
    if (threadIdx.x == 0) {
      int rank = sh_rank;
      unsigned run = 0u;
      for (int c = 0; c < 256; ++c) {
        unsigned h = hist[c];
        if (run + h > (unsigned)rank) {
          sh_rank = rank - (int)run;
          sh_prefix = prefix | ((unsigned)c << shift);
          break;
        }
        run += h;
      }
    }
    __syncthreads();
  }
  if (threadIdx.x == 0) {
    float med = __uint_as_float(sh_prefix);
    scale[t] = fmaxf(med, 1e-6f);
  }
}

// ---------------------------------------------------------------------------
// Kernel D: cosine similarity + rigidity loss, deterministic block partials
// ---------------------------------------------------------------------------
__global__ __launch_bounds__(256) void cos_loss_kernel(
    const float* __restrict__ featT, const int* __restrict__ idxw,
    const float* __restrict__ norms, const float* __restrict__ dv,
    const float* __restrict__ scale, float* __restrict__ partial) {
  const int w = threadIdx.x >> 6, lane = threadIdx.x & 63;
  __shared__ float wsum[4];
  float acc = 0.0f;
  const int qbase = blockIdx.x * QPB + w * (QPB / 4);
  for (int i = 0; i < QPB / 4; ++i) {
    const int g = qbase + i;
    const int t = g >> 14;
    const int p = g & (PP - 1);
    const int slice = g - p;  // base of this (t,b) slice
    const float* fbase = featT + (size_t)g * DD;
    float2 fq = *(const float2*)(fbase + lane * 2);
    float nq = fmaxf(norms[g], 1e-8f);
    const int* ip = idxw + (size_t)g * KK;
    float msum = 0.0f;
#pragma unroll
    for (int k = 0; k < KK; ++k) {
      int j = ip[k];
      const float* nb = featT + (size_t)(slice + j) * DD;
      float2 fn = *(const float2*)(nb + lane * 2);
      float part = fmaf(fq.x, fn.x, fq.y * fn.y);
#pragma unroll
      for (int o = 32; o > 0; o >>= 1) part += __shfl_xor(part, o);
      float nn = fmaxf(norms[slice + j], 1e-8f);
      msum += part / (nq * nn);
    }
    float mean_sim = msum * (1.0f / KK);
    float rig = expf(-dv[g] / scale[t]);
    acc += rig * (1.0f - mean_sim);
  }
  if (lane == 0) wsum[w] = acc;
  __syncthreads();
  if (threadIdx.x == 0)
    partial[blockIdx.x] = (wsum[0] + wsum[1]) + (wsum[2] + wsum[3]);
}

// ---------------------------------------------------------------------------
// Kernel E: final deterministic reduce -> scalar loss
// ---------------------------------------------------------------------------
__global__ __launch_bounds__(256) void final_reduce_kernel(
    const float* __restrict__ partial, float* __restrict__ out) {
  __shared__ float sh[256];
  float s = 0.0f;
  for (int i = threadIdx.x; i < NBLK_COS; i += 256) s += partial[i];
  sh[threadIdx.x] = s;
  __syncthreads();
  for (int st = 128; st > 0; st >>= 1) {
    if (threadIdx.x < st) sh[threadIdx.x] += sh[threadIdx.x + st];
    __syncthreads();
  }
  if (threadIdx.x == 0) out[0] = sh[0] * (1.0f / (float)NQ);
}

extern "C" void kernel_launch(void* const* d_in, const int* in_sizes, int n_in,
                              void* d_out, int out_size, void* d_ws,
                              size_t ws_size, hipStream_t stream) {
  const float* encoded = (const float*)d_in[0];
  const float* pts4 = (const float*)d_in[1];
  char* ws = (char*)d_ws;
  float* featT = (float*)(ws + OFF_FEATT);
  unsigned* part = (unsigned*)(ws + OFF_PARTV);       // aliases featT
  float4* cand4 = (float4*)(ws + OFF_CAND4);          // aliases featT
  float* tau_arr = (float*)(ws + OFF_TAU);            // aliases featT
  unsigned* fcnt = (unsigned*)(ws + OFF_FCNT);        // aliases featT
  unsigned short* flist = (unsigned short*)(ws + OFF_FLIST);  // aliases featT
  int* idxw = (int*)(ws + OFF_IDX);
  float* dv = (float*)(ws + OFF_DV);
  float* norms = (float*)(ws + OFF_NORM);
  float* scale = (float*)(ws + OFF_SCALE);
  float* partial = (float*)(ws + OFF_PART);
  float* outp = (float*)d_out;

  prep_cand<<<(BB * TT * PP) / 256, 256, 0, stream>>>(pts4, cand4);
  knn_thr_partial<<<dim3(16 * CHUNKS, BB, NT), 256, 0, stream>>>(cand4, part);
  tau_kernel<<<NQ / 256, 256, 0, stream>>>(part, tau_arr);
  knn_filter<<<dim3(16 * CHUNKS, BB, NT), 256, 0, stream>>>(cand4, tau_arr,
                                                            fcnt, flist);
  knn_finish<<<NQ / 256, 256, 0, stream>>>(cand4, pts4, fcnt, flist, idxw, dv);
  transpose_kernel<<<dim3(PP / 32, DD / 32, NT * BB), dim3(32, 8), 0, stream>>>(
      encoded, featT);
  norms_kernel<<<NBLK_COS, 256, 0, stream>>>(featT, norms);
  median_kernel<<<NT, 256, 0, stream>>>(dv, scale);
  cos_loss_kernel<<<NBLK_COS, 256, 0, stream>>>(featT, idxw, norms, dv, scale,
                                                partial);
  final_reduce_kernel<<<1, 256, 0, stream>>>(partial, outp);
}

// Round 9
// 676.414 us; speedup vs baseline: 1.1606x; 1.0906x over previous
//
#include <hip/hip_runtime.h>
#include <math.h>

// Problem constants (fixed by setup_inputs: B=4, D=128, T=8, P=4096)
#define BB 4
#define DD 128
#define TT 8
#define PP 4096
#define KK 10
#define NT 7              // T-1 frame pairs
#define BP (BB*PP)        // 16384 points per frame across batch
#define NQ (NT*BP)        // 114688 total queries
#define NBLK_COS 896
#define QPB 128           // queries per block in cos kernel (NBLK_COS*QPB == NQ)

#define CHUNKS 4
#define CSZ (PP/CHUNKS)   // 1024 candidates per chunk
#define FCAP 12           // per-chunk recorded-index cap (typ ~3, worst ~11)

// Workspace layout (bytes). Everything below OFF_IDX aliases the featT
// region (58.7 MB) and is fully consumed by knn_finish BEFORE
// transpose_kernel writes featT (same-stream ordering).
#define OFF_FEATT 0u                 // NQ*DD floats  = 58,720,256 B
#define OFF_PARTV 0u                 // CHUNKS*KK*NQ uints = 18,350,080 B
#define OFF_CAND4 20971520u          // BB*TT*PP float4 = 2,097,152 B
#define OFF_TAU   23068672u          // NQ floats = 458,752 B
#define OFF_FCNT  23527424u          // CHUNKS*NQ uints = 1,835,008 B
#define OFF_FLIST 25362432u          // CHUNKS*FCAP*NQ u16 = 11,010,048 B (ends 36.4 MB)
#define OFF_IDX   58720256u          // NQ*KK ints    =  4,587,520 B
#define OFF_DV    63307776u          // NQ floats     =    458,752 B
#define OFF_NORM  63766528u          // NQ floats     =    458,752 B
#define OFF_SCALE 64225280u          // NT floats (padded to 256)
#define OFF_PART  64225536u          // NBLK_COS floats

// __builtin_amdgcn_cvt_pkrtz returns __fp16 ext_vector_type(2).
typedef __fp16 f16x2 __attribute__((ext_vector_type(2)));
union H2U { f16x2 h; unsigned u; };

// Packed f16 min/max via inline asm: clang promotes __builtin_elementwise_*
// on f16 vectors to f32 (round-8 post-mortem: 2.8x VALU inflation). VOP3P
// v_pk_min_f16/v_pk_max_f16 are 1 instruction for 2 lanes' worth of ladder.
// Semantics match promoted-f32 min/max for our ordered finite values, so all
// stored bounds / tau stay bit-identical to round 8.
__device__ __forceinline__ f16x2 pk_min(f16x2 a, f16x2 b) {
  f16x2 d;
  asm("v_pk_min_f16 %0, %1, %2" : "=v"(d) : "v"(a), "v"(b));
  return d;
}
__device__ __forceinline__ f16x2 pk_max(f16x2 a, f16x2 b) {
  f16x2 d;
  asm("v_pk_max_f16 %0, %1, %2" : "=v"(d) : "v"(a), "v"(b));
  return d;
}

// md = |q-c|^2 computed as (xx_q + xx_c) - 2*inner. MUST be the same
// expression in every kernel (bit-identical md values are what make the
// f16-upper-bound threshold argument exact). Self-distance is exactly 0:
// prep's xx uses the identical fmaf chain as inner at j==p.
__device__ __forceinline__ float md_of(const float4 q, const float4 c) {
  float s = q.w + c.w;
  float inner = fmaf(q.x, c.x, fmaf(q.y, c.y, q.z * c.z));
  return fmaf(-2.0f, inner, s);
}

// Packed-f16 "keep 10 smallest" ladder over two independent candidate
// streams (.x / .y). Values are conservative UPPER bounds of md:
// cvt_pkrtz (round toward zero = down for positives) then +2 f16-ulps.
// ub(md) is monotone non-decreasing in md. 21 VALU per 2 candidates.
__device__ __forceinline__ void ins2(f16x2 (&bv)[KK], float mdA, float mdB) {
  H2U cv;
  cv.h = __builtin_amdgcn_cvt_pkrtz(mdA, mdB);
  cv.u += 0x00020002u;  // +2 ulps up (values small positive; no NaN/ovf)
  bv[KK - 1] = pk_min(bv[KK - 1], cv.h);
#pragma unroll
  for (int i = KK - 1; i > 0; --i) {
    f16x2 lo = pk_min(bv[i - 1], bv[i]);
    f16x2 hi = pk_max(bv[i - 1], bv[i]);
    bv[i - 1] = lo;
    bv[i] = hi;
  }
}
__device__ __forceinline__ void insh(f16x2 (&bv)[KK], f16x2 h) {
  bv[KK - 1] = pk_min(bv[KK - 1], h);
#pragma unroll
  for (int i = KK - 1; i > 0; --i) {
    f16x2 lo = pk_min(bv[i - 1], bv[i]);
    f16x2 hi = pk_max(bv[i - 1], bv[i]);
    bv[i - 1] = lo;
    bv[i] = hi;
  }
}

// f32 keep-10-smallest (values only), branchless.
__device__ __forceinline__ void insf(float (&bv)[KK], float v) {
  bv[KK - 1] = fminf(bv[KK - 1], v);
#pragma unroll
  for (int i = KK - 1; i > 0; --i) {
    float lo = fminf(bv[i - 1], bv[i]);
    float hi = fmaxf(bv[i - 1], bv[i]);
    bv[i - 1] = lo;
    bv[i] = hi;
  }
}

// Exact stable (md,idx) insert: keep 10 smallest, ascending md; strict-<
// entry/bubble over an ascending-j insert stream keeps earlier index on
// ties — exactly jax.lax.top_k's tie rule.
__device__ __forceinline__ void insp(float (&v)[KK], int (&vi)[KK], float md,
                                     int j) {
  bool en = md < v[KK - 1];
  v[KK - 1] = en ? md : v[KK - 1];
  vi[KK - 1] = en ? j : vi[KK - 1];
#pragma unroll
  for (int i = KK - 1; i > 0; --i) {
    bool sw = v[i] < v[i - 1];
    float tv = sw ? v[i - 1] : v[i];
    v[i - 1] = sw ? v[i] : v[i - 1];
    v[i] = tv;
    int ti = sw ? vi[i - 1] : vi[i];
    vi[i - 1] = sw ? vi[i] : vi[i - 1];
    vi[i] = ti;
  }
}

// Register scatter by runtime slot (unroll-literal indices -> stays in VGPRs).
__device__ __forceinline__ void rec12(int (&a)[FCAP], int cnt, int j) {
#pragma unroll
  for (int r = 0; r < FCAP; ++r) a[r] = (cnt == r) ? j : a[r];
}

// ---------------------------------------------------------------------------
// Kernel P: precompute (x,y,z,xx) per point.
// ---------------------------------------------------------------------------
__global__ __launch_bounds__(256) void prep_cand(
    const float* __restrict__ pts4, float4* __restrict__ cand4) {
  const int i = blockIdx.x * 256 + threadIdx.x;  // over BB*TT*PP
  float4 v = ((const float4*)pts4)[i];
  v.w = fmaf(v.x, v.x, fmaf(v.y, v.y, v.z * v.z));
  cand4[i] = v;
}

// ---------------------------------------------------------------------------
// Kernel A1: per-chunk top-10 conservative f16 upper bounds of md (no LDS;
// two packed ladders = 4 virtual streams, merged to 2 before store).
// ---------------------------------------------------------------------------
__global__ __launch_bounds__(256) void knn_thr_partial(
    const float4* __restrict__ cand4, unsigned* __restrict__ part) {
  const int qg = blockIdx.x >> 2;  // query group 0..15
  const int c = blockIdx.x & 3;    // chunk 0..3
  const int b = blockIdx.y, t = blockIdx.z;
  const float4* __restrict__ src = cand4 + ((size_t)(b * TT + t) * PP);
  const float4* __restrict__ ch = src + c * CSZ;

  const int p = qg * 256 + threadIdx.x;
  const float4 q = src[p];

  H2U inf2;
  inf2.u = 0x7C007C00u;
  f16x2 l1[KK], l2[KK];
#pragma unroll
  for (int i = 0; i < KK; ++i) { l1[i] = inf2.h; l2[i] = inf2.h; }

  for (int j = 0; j < CSZ; j += 4) {
    float4 c0 = ch[j], c1 = ch[j + 1], c2 = ch[j + 2], c3 = ch[j + 3];
    float md0 = md_of(q, c0);
    float md1 = md_of(q, c1);
    float md2 = md_of(q, c2);
    float md3 = md_of(q, c3);
    ins2(l1, md0, md1);
    ins2(l2, md2, md3);
  }
  // merge stream-pairs: l1 <- per-component union top-10
#pragma unroll
  for (int r = 0; r < KK; ++r) insh(l1, l2[r]);

  const size_t qid = (size_t)(t * BB + b) * PP + p;
#pragma unroll
  for (int r = 0; r < KK; ++r) {
    H2U w;
    w.h = l1[r];
    part[(size_t)(c * KK + r) * NQ + qid] = w.u;
  }
}

// ---------------------------------------------------------------------------
// Kernel T: tau[g] = 10th-smallest of the 80 stored f16 upper bounds + eps.
// Guarantee: every true top-10 member m has md_m <= tau (ub monotone in md,
// so at most 9 stored values are strictly below ub(md_10)).
// ---------------------------------------------------------------------------
__global__ __launch_bounds__(256) void tau_kernel(
    const unsigned* __restrict__ part, float* __restrict__ tau_arr) {
  const int g = blockIdx.x * 256 + threadIdx.x;
  float bv[KK];
#pragma unroll
  for (int i = 0; i < KK; ++i) bv[i] = INFINITY;
#pragma unroll
  for (int c = 0; c < CHUNKS; ++c) {
#pragma unroll
    for (int r = 0; r < KK; ++r) {
      H2U w;
      w.u = part[(size_t)(c * KK + r) * NQ + g];
      insf(bv, (float)w.h.x);
      insf(bv, (float)w.h.y);
    }
  }
  tau_arr[g] = bv[KK - 1] + 1e-4f;
}

// ---------------------------------------------------------------------------
// Kernel F: chunked filter. Each block scans ONE 1024-candidate chunk for
// 256 queries; records global indices with md <= tau (<=12/chunk, asc j).
// ---------------------------------------------------------------------------
__global__ __launch_bounds__(256) void knn_filter(
    const float4* __restrict__ cand4, const float* __restrict__ tau_arr,
    unsigned* __restrict__ fcnt, unsigned short* __restrict__ flist) {
  const int qg = blockIdx.x >> 2;  // query group 0..15
  const int c = blockIdx.x & 3;    // chunk 0..3
  const int b = blockIdx.y, t = blockIdx.z;
  const float4* __restrict__ src = cand4 + ((size_t)(b * TT + t) * PP);
  const float4* __restrict__ ch = src + c * CSZ;
  const int jbase = c * CSZ;

  const int p = qg * 256 + threadIdx.x;
  const size_t g = (size_t)(t * BB + b) * PP + p;
  const float4 q = src[p];
  const float tau = tau_arr[g];

  int sel[FCAP];
#pragma unroll
  for (int r = 0; r < FCAP; ++r) sel[r] = 0;
  int cnt = 0;

  for (int j = 0; j < CSZ; j += 8) {
    float4 c0 = ch[j], c1 = ch[j + 1], c2 = ch[j + 2], c3 = ch[j + 3];
    float4 c4 = ch[j + 4], c5 = ch[j + 5], c6 = ch[j + 6], c7 = ch[j + 7];
    float m0 = md_of(q, c0), m1 = md_of(q, c1), m2 = md_of(q, c2),
          m3 = md_of(q, c3);
    float m4 = md_of(q, c4), m5 = md_of(q, c5), m6 = md_of(q, c6),
          m7 = md_of(q, c7);
#define FLT(mm, jj)                                         \
    if ((mm) <= tau) { rec12(sel, cnt, jbase + (jj)); ++cnt; }
    FLT(m0, j); FLT(m1, j + 1); FLT(m2, j + 2); FLT(m3, j + 3);
    FLT(m4, j + 4); FLT(m5, j + 5); FLT(m6, j + 6); FLT(m7, j + 7);
#undef FLT
  }

  fcnt[(size_t)c * NQ + g] = (unsigned)cnt;
#pragma unroll
  for (int r = 0; r < FCAP; ++r)
    flist[(size_t)(c * FCAP + r) * NQ + g] = (unsigned short)sel[r];
}

// ---------------------------------------------------------------------------
// Kernel G: finish. Per query: gather the <=48 recorded candidates
// (ascending j across chunks), exact stable (md,idx) top-10, disp_var.
// ---------------------------------------------------------------------------
__global__ __launch_bounds__(256) void knn_finish(
    const float4* __restrict__ cand4, const float* __restrict__ pts4,
    const unsigned* __restrict__ fcnt, const unsigned short* __restrict__ flist,
    int* __restrict__ idx_out, float* __restrict__ dv_out) {
  const int g = blockIdx.x * 256 + threadIdx.x;
  const int t = g >> 14;
  const int rem = g & (BP - 1);
  const int b = rem >> 12;
  const int p = rem & (PP - 1);
  const float4* __restrict__ src = cand4 + ((size_t)(b * TT + t) * PP);
  const float4* __restrict__ src1 =
      (const float4*)pts4 + ((size_t)(b * TT + t + 1) * PP);

  const float4 q = src[p];

  float v[KK];
  int vi[KK];
#pragma unroll
  for (int i = 0; i < KK; ++i) { v[i] = INFINITY; vi[i] = 0; }

#pragma unroll
  for (int c = 0; c < CHUNKS; ++c) {
    int cn = (int)fcnt[(size_t)c * NQ + g];
    cn = cn < FCAP ? cn : FCAP;
#pragma unroll
    for (int r = 0; r < FCAP; ++r) {
      if (r < cn) {
        int j = (int)flist[(size_t)(c * FCAP + r) * NQ + g];
        insp(v, vi, md_of(q, src[j]), j);
      }
    }
  }

  // disp_var over the 10 selected, in rank order (matches top_k order)
  float4 a1 = src1[p];
  const float dqx = a1.x - q.x, dqy = a1.y - q.y, dqz = a1.z - q.z;
  float s = 0.0f;
  int* myidx = idx_out + (size_t)g * KK;
#pragma unroll
  for (int r = 0; r < KK; ++r) {
    int j = vi[r];
    float4 cc = src[j];
    float4 n1 = src1[j];
    float dx = (n1.x - cc.x) - dqx;
    float dy = (n1.y - cc.y) - dqy;
    float dz = (n1.z - cc.z) - dqz;
    s += fmaf(dx, dx, fmaf(dy, dy, dz * dz));
    myidx[r] = j;
  }
  dv_out[g] = s * (1.0f / KK);
}

// ---------------------------------------------------------------------------
// Kernel B2: transpose encoded[b][d][t*P+p] -> featT[t][b][p][d]  (t < NT)
// ---------------------------------------------------------------------------
__global__ __launch_bounds__(256) void transpose_kernel(
    const float* __restrict__ encoded, float* __restrict__ featT) {
  __shared__ float tile[32][33];
  const int slice = blockIdx.z;  // t*BB + b
  const int t = slice / BB, b = slice % BB;
  const int p0 = blockIdx.x * 32, d0 = blockIdx.y * 32;
  const int tx = threadIdx.x, ty = threadIdx.y;
#pragma unroll
  for (int r = 0; r < 4; ++r) {
    int d = d0 + ty + r * 8;
    tile[ty + r * 8][tx] =
        encoded[((size_t)(b * DD + d)) * (TT * PP) + (size_t)t * PP + p0 + tx];
  }
  __syncthreads();
#pragma unroll
  for (int r = 0; r < 4; ++r) {
    int p = p0 + ty + r * 8;
    featT[((size_t)slice * PP + p) * DD + d0 + tx] = tile[tx][ty + r * 8];
  }
}

// ---------------------------------------------------------------------------
// Kernel N: per-point feature L2 norms (wave per point)
// ---------------------------------------------------------------------------
__global__ __launch_bounds__(256) void norms_kernel(
    const float* __restrict__ featT, float* __restrict__ norms) {
  const int w = threadIdx.x >> 6, lane = threadIdx.x & 63;
  const int wid = blockIdx.x * 4 + w;
  for (int i = 0; i < 32; ++i) {
    const int g = wid * 32 + i;
    float2 f = *(const float2*)(featT + (size_t)g * DD + lane * 2);
    float part = fmaf(f.x, f.x, f.y * f.y);
#pragma unroll
    for (int o = 32; o > 0; o >>= 1) part += __shfl_xor(part, o);
    if (lane == 0) norms[g] = sqrtf(part);
  }
}

// ---------------------------------------------------------------------------
// Kernel C: exact lower-median per t via 4-pass radix select on float bits
// ---------------------------------------------------------------------------
__global__ __launch_bounds__(256) void median_kernel(
    const float* __restrict__ disp_var, float* __restrict__ scale) {
  const int t = blockIdx.x;
  const unsigned* u = (const unsigned*)(disp_var + (size_t)t * BP);
  __shared__ unsigned hist[256];
  __shared__ unsigned sh_prefix;
  __shared__ int sh_rank;
  if (threadIdx.x == 0) { sh_prefix = 0u; sh_rank = (BP - 1) >> 1; }
  __syncthreads();
  for (int pass = 0; pass < 4; ++pass) {
    const int shift = 24 - pass * 8;
    hist[threadIdx.x] = 0u;
    __syncthreads();
    const unsigned hmask = (pass == 0) ? 0u : (0xFFFFFFFFu << (shift + 8));
    const unsigned prefix = sh_prefix;
    for (int i = threadIdx.x; i < BP; i += 256) {
      unsigned v = u[i];
      if ((v & hmask) == prefix) atomicAdd(&hist[(v >> shift) & 255u], 1u);
    }
    __syncthreads();
    if (threadIdx.x == 0) {
      int rank = sh_rank;
      unsigned run = 0u;
      for (int c = 0; c < 256; ++c) {
        unsigned h = hist[c];
        if (run + h > (unsigned)rank) {
          sh_rank = rank - (int)run;
          sh_prefix = prefix | ((unsigned)c << shift);
          break;
        }
        run += h;
      }
    }
    __syncthreads();
  }
  if (threadIdx.x == 0) {
    float med = __uint_as_float(sh_prefix);
    scale[t] = fmaxf(med, 1e-6f);
  }
}

// ---------------------------------------------------------------------------
// Kernel D: cosine similarity + rigidity loss, deterministic block partials
// ---------------------------------------------------------------------------
__global__ __launch_bounds__(256) void cos_loss_kernel(
    const float* __restrict__ featT, const int* __restrict__ idxw,
    const float* __restrict__ norms, const float* __restrict__ dv,
    const float* __restrict__ scale, float* __restrict__ partial) {
  const int w = threadIdx.x >> 6, lane = threadIdx.x & 63;
  __shared__ float wsum[4];
  float acc = 0.0f;
  const int qbase = blockIdx.x * QPB + w * (QPB / 4);
  for (int i = 0; i < QPB / 4; ++i) {
    const int g = qbase + i;
    const int t = g >> 14;
    const int p = g & (PP - 1);
    const int slice = g - p;  // base of this (t,b) slice
    const float* fbase = featT + (size_t)g * DD;
    float2 fq = *(const float2*)(fbase + lane * 2);
    float nq = fmaxf(norms[g], 1e-8f);
    const int* ip = idxw + (size_t)g * KK;
    float msum = 0.0f;
#pragma unroll
    for (int k = 0; k < KK; ++k) {
      int j = ip[k];
      const float* nb = featT + (size_t)(slice + j) * DD;
      float2 fn = *(const float2*)(nb + lane * 2);
      float part = fmaf(fq.x, fn.x, fq.y * fn.y);
#pragma unroll
      for (int o = 32; o > 0; o >>= 1) part += __shfl_xor(part, o);
      float nn = fmaxf(norms[slice + j], 1e-8f);
      msum += part / (nq * nn);
    }
    float mean_sim = msum * (1.0f / KK);
    float rig = expf(-dv[g] / scale[t]);
    acc += rig * (1.0f - mean_sim);
  }
  if (lane == 0) wsum[w] = acc;
  __syncthreads();
  if (threadIdx.x == 0)
    partial[blockIdx.x] = (wsum[0] + wsum[1]) + (wsum[2] + wsum[3]);
}

// ---------------------------------------------------------------------------
// Kernel E: final deterministic reduce -> scalar loss
// ---------------------------------------------------------------------------
__global__ __launch_bounds__(256) void final_reduce_kernel(
    const float* __restrict__ partial, float* __restrict__ out) {
  __shared__ float sh[256];
  float s = 0.0f;
  for (int i = threadIdx.x; i < NBLK_COS; i += 256) s += partial[i];
  sh[threadIdx.x] = s;
  __syncthreads();
  for (int st = 128; st > 0; st >>= 1) {
    if (threadIdx.x < st) sh[threadIdx.x] += sh[threadIdx.x + st];
    __syncthreads();
  }
  if (threadIdx.x == 0) out[0] = sh[0] * (1.0f / (float)NQ);
}

extern "C" void kernel_launch(void* const* d_in, const int* in_sizes, int n_in,
                              void* d_out, int out_size, void* d_ws,
                              size_t ws_size, hipStream_t stream) {
  const float* encoded = (const float*)d_in[0];
  const float* pts4 = (const float*)d_in[1];
  char* ws = (char*)d_ws;
  float* featT = (float*)(ws + OFF_FEATT);
  unsigned* part = (unsigned*)(ws + OFF_PARTV);       // aliases featT
  float4* cand4 = (float4*)(ws + OFF_CAND4);          // aliases featT
  float* tau_arr = (float*)(ws + OFF_TAU);            // aliases featT
  unsigned* fcnt = (unsigned*)(ws + OFF_FCNT);        // aliases featT
  unsigned short* flist = (unsigned short*)(ws + OFF_FLIST);  // aliases featT
  int* idxw = (int*)(ws + OFF_IDX);
  float* dv = (float*)(ws + OFF_DV);
  float* norms = (float*)(ws + OFF_NORM);
  float* scale = (float*)(ws + OFF_SCALE);
  float* partial = (float*)(ws + OFF_PART);
  float* outp = (float*)d_out;

  prep_cand<<<(BB * TT * PP) / 256, 256, 0, stream>>>(pts4, cand4);
  knn_thr_partial<<<dim3(16 * CHUNKS, BB, NT), 256, 0, stream>>>(cand4, part);
  tau_kernel<<<NQ / 256, 256, 0, stream>>>(part, tau_arr);
  knn_filter<<<dim3(16 * CHUNKS, BB, NT), 256, 0, stream>>>(cand4, tau_arr,
                                                            fcnt, flist);
  knn_finish<<<NQ / 256, 256, 0, stream>>>(cand4, pts4, fcnt, flist, idxw, dv);
  transpose_kernel<<<dim3(PP / 32, DD / 32, NT * BB), dim3(32, 8), 0, stream>>>(
      encoded, featT);
  norms_kernel<<<NBLK_COS, 256, 0, stream>>>(featT, norms);
  median_kernel<<<NT, 256, 0, stream>>>(dv, scale);
  cos_loss_kernel<<<NBLK_COS, 256, 0, stream>>>(featT, idxw, norms, dv, scale,
                                                partial);
  final_reduce_kernel<<<1, 256, 0, stream>>>(partial, outp);
}